// Round 6
// baseline (136.166 us; speedup 1.0000x reference)
//
#include <hip/hip_runtime.h>

#define NT 4096
#define NPP 100
#define NROWS 2048
#define BLK 256
#define EPT 16           // 256*16 = 4096
#define NM 98            // interior spline unknowns
#define DTIME 0.001f
#define HF (1.0f / 99.0f)

// Inverse kernel of tridiag(1,4,1): G(d) = r^|d| / (2*sqrt(3)), r = sqrt(3)-2.
// Truncated at |d|=12 (rel err ~4e-8). Sum over all d = 1/6.
__device__ __constant__ float GW[13] = {
    0.288675135f,    -0.077350269f,   0.020725943f,   -0.0055534374f,
    0.0014880647f,   -0.00039874667f, 0.00010684152f, -2.8626968e-05f,
    7.6707195e-06f,  -2.0554928e-06f, 5.5072549e-07f, -1.4756630e-07f,
    3.9539424e-08f};

__global__ __launch_bounds__(BLK) void wass_row_kernel(
    const float* __restrict__ f, const float* __restrict__ obs,
    float* __restrict__ rowOut, unsigned* __restrict__ counter,
    float* __restrict__ out) {
  const int row  = blockIdx.x;
  const int tid  = threadIdx.x;
  const int lane = tid & 63;
  const int wid  = tid >> 6;

  __shared__ float  sQ[NPP];
  __shared__ float  sM[NPP];
  __shared__ float  sRhs[NM];
  __shared__ float4 sCo[NPP - 1];
  __shared__ float  sFlast[BLK];
  __shared__ float  sWo[4], sWf[4], sWoOff[4], sWfOff[4];
  __shared__ float  sTotO, sTotF, sY0o, sYlo, sY0f, sYlf;
  __shared__ int    sIsLast;
  __shared__ double sDW[4];

  // ---- issue BOTH rows' loads up front ----
  float yo[EPT], yf[EPT];
  {
    const float4* op = (const float4*)(obs + (size_t)row * NT);
    const float4* fp = (const float4*)(f + (size_t)row * NT);
    float4 vo[4], vf[4];
#pragma unroll
    for (int q = 0; q < 4; ++q) vo[q] = op[tid * 4 + q];
#pragma unroll
    for (int q = 0; q < 4; ++q) vf[q] = fp[tid * 4 + q];
#pragma unroll
    for (int q = 0; q < 4; ++q) {
      yo[4*q+0] = fabsf(vo[q].x); yo[4*q+1] = fabsf(vo[q].y);
      yo[4*q+2] = fabsf(vo[q].z); yo[4*q+3] = fabsf(vo[q].w);
      yf[4*q+0] = fabsf(vf[q].x); yf[4*q+1] = fabsf(vf[q].y);
      yf[4*q+2] = fabsf(vf[q].z); yf[4*q+3] = fabsf(vf[q].w);
    }
  }

  // ---- fused block scan of per-thread sums ----
  float so = 0.f, sf = 0.f;
#pragma unroll
  for (int j = 0; j < EPT; ++j) { so += yo[j]; sf += yf[j]; }
  float vo = so, vf = sf;
#pragma unroll
  for (int off = 1; off < 64; off <<= 1) {
    float no = __shfl_up(vo, off, 64);
    float nf = __shfl_up(vf, off, 64);
    if (lane >= off) { vo += no; vf += nf; }
  }
  if (lane == 63) { sWo[wid] = vo; sWf[wid] = vf; }
  if (tid == 0)       { sY0o = yo[0];       sY0f = yf[0]; }
  if (tid == BLK - 1) { sYlo = yo[EPT - 1]; sYlf = yf[EPT - 1]; }
  __syncthreads();
  if (tid == 0) {
    float a = 0.f, b = 0.f;
#pragma unroll
    for (int w = 0; w < 4; ++w) {
      sWoOff[w] = a; a += sWo[w];
      sWfOff[w] = b; b += sWf[w];
    }
    sTotO = a; sTotF = b;
  }
  __syncthreads();

  const float exO0 = (vo - so) + sWoOff[wid];
  const float exF0 = (vf - sf) + sWfOff[wid];
  const float y0f  = sY0f;
  const float TrF  = sTotF - 0.5f * (sY0f + sYlf);
  const float invTF = 1.0f / TrF;

  // ---- obs CDF as a register chain (overwrites yo[]); publish last ----
  {
    const float invT = 1.0f / (sTotO - 0.5f * (sY0o + sYlo));
    const float hInv = 0.5f * invT;
    const float c0   = sY0o * hInv;
    float ex = exO0;
#pragma unroll
    for (int j = 0; j < EPT; ++j) {
      float yv = yo[j];
      yo[j] = fmaf(ex, invT, fmaf(yv, hInv, -c0));  // F[tid*16+j]
      ex += yv;
    }
    sFlast[tid] = yo[EPT - 1];
  }
  if (tid == 0) sQ[0] = 0.0f;  // p_0 = 0 = F_0 -> t_0 = 0
  __syncthreads();

  // ---- interval-ownership inverse CDF: thread owns (F[k0-1], F[k0]] ----
  {
    float a = (tid == 0) ? 0.0f : sFlast[tid - 1];
    int kprev = (int)floorf(a * 99.0f);
    if (kprev < 0) kprev = 0;
    const int base = tid * EPT;
#pragma unroll
    for (int j = 0; j < EPT; ++j) {
      float b = yo[j];
      int k0 = base + j;
      int kb = (int)floorf(b * 99.0f);
      if (kb > 99) kb = 99;
      if (k0 == NT - 1) kb = 99;  // force tail coverage (np.interp clamp)
      if (kb > kprev) {
        float denom = b - a;
        float tPrev = (float)(k0 - 1) * DTIME;
        bool ok = denom > 0.f;
        float rd = ok ? 1.0f / denom : 0.0f;
        for (int k = kprev + 1; k <= kb; ++k) {
          float pk = (float)k * HF;
          float r = ok ? (pk - a) * rd : 1.0f;
          r = fminf(r, 1.0f);  // np.interp clamps beyond xp[-1]
          sQ[k] = fmaf(r, DTIME, tPrev);
        }
        kprev = kb;
      }
      a = b;
    }
  }
  __syncthreads();

  // ---- rhs of tridiag system ----
  if (tid < NM) {
    sRhs[tid] = (6.0f * 99.0f * 99.0f) *
                (sQ[tid + 2] - 2.0f * sQ[tid + 1] + sQ[tid]);
  }
  __syncthreads();

  // ---- tridiag(1,4,1) solve = 25-tap constant convolution + odd images ----
  if (tid < NM) {
    float m = 0.f;
#pragma unroll
    for (int d = -12; d <= 12; ++d) {
      int j = tid + d;
      bool neg = (j < 0), pos = (j > NM - 1);
      int jr = neg ? (-2 - j) : (pos ? (2 * NM - j) : j);
      jr = jr < 0 ? 0 : (jr > NM - 1 ? NM - 1 : jr);
      bool z = (j == -1) || (j == NM);
      float v = sRhs[jr];
      v = (neg || pos) ? -v : v;
      v = z ? 0.f : v;
      m = fmaf(GW[d < 0 ? -d : d], v, m);
    }
    sM[tid + 1] = m;
  }
  if (tid == NM) { sM[0] = 0.f; sM[NPP - 1] = 0.f; }
  __syncthreads();

  // ---- spline coefficients (float4-packed) ----
  if (tid < NPP - 1) {
    float yi = sQ[tid], yi1 = sQ[tid + 1];
    float Mi = sM[tid], Mi1 = sM[tid + 1];
    float4 co;
    co.x = yi;
    co.y = (yi1 - yi) * 99.0f - HF * (2.0f * Mi + Mi1) * (1.0f / 6.0f);
    co.z = 0.5f * Mi;
    co.w = (Mi1 - Mi) * (99.0f / 6.0f);
    sCo[tid] = co;
  }
  __syncthreads();

  // ---- Phase B: f CDF -> spline eval -> accumulation ----
  float acc = 0.f;
  {
    const float hInv = 0.5f * invTF;
    const float c0   = y0f * hInv;
    float ex = exF0;
    const float tBase = (float)(tid * EPT) * DTIME;
#pragma unroll
    for (int j = 0; j < EPT; ++j) {
      float yv = yf[j];
      float Fk = fmaf(ex, invTF, fmaf(yv, hInv, -c0));
      ex += yv;
      float xi = fminf(fmaxf(Fk, 0.f), 1.f);
      int idx = (int)(xi * 99.0f);
      if (idx > NPP - 2) idx = NPP - 2;
      float dxv = fmaf(-(float)idx, HF, xi);
      float4 co = sCo[idx];
      float val = fmaf(dxv, fmaf(dxv, fmaf(dxv, co.w, co.z), co.y), co.x);
      float diff = fmaf((float)j, DTIME, tBase) - val;
      acc = fmaf(diff * diff, yv, acc);
    }
  }

  // ---- block reduce -> per-row partial + last-block-done final reduce ----
#pragma unroll
  for (int off = 32; off > 0; off >>= 1) acc += __shfl_down(acc, off, 64);
  if (lane == 0) sWo[wid] = acc;
  __syncthreads();
  if (tid == 0) {
    float part = (sWo[0] + sWo[1] + sWo[2] + sWo[3]) * invTF;
    // agent-scope store, then release via the counter increment (G16:
    // cross-XCD visibility needs device-scope release/acquire)
    __hip_atomic_store(&rowOut[row], part, __ATOMIC_RELAXED,
                       __HIP_MEMORY_SCOPE_AGENT);
    unsigned prev = __hip_atomic_fetch_add(counter, 1u, __ATOMIC_ACQ_REL,
                                           __HIP_MEMORY_SCOPE_AGENT);
    sIsLast = (prev == NROWS - 1);
  }
  __syncthreads();

  if (sIsLast) {
    // exactly one block reaches here, after all partials are released.
    // Deterministic: fixed read order + fixed shuffle tree, double accum.
    double dacc = 0.0;
    for (int i = tid; i < NROWS; i += BLK) {
      float v = __hip_atomic_load(&rowOut[i], __ATOMIC_RELAXED,
                                  __HIP_MEMORY_SCOPE_AGENT);
      dacc += (double)v;
    }
#pragma unroll
    for (int off = 32; off > 0; off >>= 1) dacc += __shfl_down(dacc, off, 64);
    if (lane == 0) sDW[wid] = dacc;
    __syncthreads();
    if (tid == 0) out[0] = (float)(sDW[0] + sDW[1] + sDW[2] + sDW[3]);
  }
}

extern "C" void kernel_launch(void* const* d_in, const int* in_sizes, int n_in,
                              void* d_out, int out_size, void* d_ws, size_t ws_size,
                              hipStream_t stream) {
  (void)in_sizes; (void)n_in; (void)out_size; (void)ws_size;
  const float* f   = (const float*)d_in[0];
  const float* obs = (const float*)d_in[1];
  // d_in[2] (t) is analytic: t[k] = k * 0.001f — computed inline.

  // d_ws layout: [0..3] counter (zeroed via graph-legal memset node),
  // [256..] rowOut partials (256B alignment for the partial array).
  unsigned* counter = (unsigned*)d_ws;
  float* rowOut = (float*)((char*)d_ws + 256);

  hipMemsetAsync(counter, 0, sizeof(unsigned), stream);
  wass_row_kernel<<<NROWS, BLK, 0, stream>>>(f, obs, rowOut, counter,
                                             (float*)d_out);
}

// Round 7
// 100.939 us; speedup vs baseline: 1.3490x; 1.3490x over previous
//
#include <hip/hip_runtime.h>

#define NT 4096
#define NPP 100
#define NROWS 2048
#define BLK 256
#define EPT 16           // 256*16 = 4096
#define NM 98            // interior spline unknowns
#define DTIME 0.001f
#define HF (1.0f / 99.0f)

// Inverse kernel of tridiag(1,4,1): G(d) = r^|d| / (2*sqrt(3)), r = sqrt(3)-2.
// Truncated at |d|=12 (rel err ~4e-8). Sum over all d = 1/6.
__device__ __constant__ float GW[13] = {
    0.288675135f,    -0.077350269f,   0.020725943f,   -0.0055534374f,
    0.0014880647f,   -0.00039874667f, 0.00010684152f, -2.8626968e-05f,
    7.6707195e-06f,  -2.0554928e-06f, 5.5072549e-07f, -1.4756630e-07f,
    3.9539424e-08f};

// NOTE (R4/R6 lesson): NO single-address device-scope atomics here — 2048
// blocks hitting one cacheline serialize for ~20-35 us regardless of
// atomic flavor (plain atomicAdd OR acq_rel fetch_add). Plain per-row
// stores + a tiny second kernel is strictly faster.
__global__ __launch_bounds__(BLK) void wass_row_kernel(
    const float* __restrict__ f, const float* __restrict__ obs,
    float* __restrict__ rowOut) {
  const int row  = blockIdx.x;
  const int tid  = threadIdx.x;
  const int lane = tid & 63;
  const int wid  = tid >> 6;

  __shared__ float  sQ[NPP];
  __shared__ float  sM[NPP];
  __shared__ float  sRhs[NM];
  __shared__ float4 sCo[NPP - 1];
  __shared__ float  sFlast[BLK];
  __shared__ float  sWo[4], sWf[4], sWoOff[4], sWfOff[4];
  __shared__ float  sTotO, sTotF, sY0o, sYlo, sY0f, sYlf;

  // ---- issue BOTH rows' loads up front ----
  float yo[EPT], yf[EPT];
  {
    const float4* op = (const float4*)(obs + (size_t)row * NT);
    const float4* fp = (const float4*)(f + (size_t)row * NT);
    float4 vo[4], vf[4];
#pragma unroll
    for (int q = 0; q < 4; ++q) vo[q] = op[tid * 4 + q];
#pragma unroll
    for (int q = 0; q < 4; ++q) vf[q] = fp[tid * 4 + q];
#pragma unroll
    for (int q = 0; q < 4; ++q) {
      yo[4*q+0] = fabsf(vo[q].x); yo[4*q+1] = fabsf(vo[q].y);
      yo[4*q+2] = fabsf(vo[q].z); yo[4*q+3] = fabsf(vo[q].w);
      yf[4*q+0] = fabsf(vf[q].x); yf[4*q+1] = fabsf(vf[q].y);
      yf[4*q+2] = fabsf(vf[q].z); yf[4*q+3] = fabsf(vf[q].w);
    }
  }

  // ---- fused block scan of per-thread sums ----
  float so = 0.f, sf = 0.f;
#pragma unroll
  for (int j = 0; j < EPT; ++j) { so += yo[j]; sf += yf[j]; }
  float vo = so, vf = sf;
#pragma unroll
  for (int off = 1; off < 64; off <<= 1) {
    float no = __shfl_up(vo, off, 64);
    float nf = __shfl_up(vf, off, 64);
    if (lane >= off) { vo += no; vf += nf; }
  }
  if (lane == 63) { sWo[wid] = vo; sWf[wid] = vf; }
  if (tid == 0)       { sY0o = yo[0];       sY0f = yf[0]; }
  if (tid == BLK - 1) { sYlo = yo[EPT - 1]; sYlf = yf[EPT - 1]; }
  __syncthreads();
  if (tid == 0) {
    float a = 0.f, b = 0.f;
#pragma unroll
    for (int w = 0; w < 4; ++w) {
      sWoOff[w] = a; a += sWo[w];
      sWfOff[w] = b; b += sWf[w];
    }
    sTotO = a; sTotF = b;
  }
  __syncthreads();

  const float exO0 = (vo - so) + sWoOff[wid];
  const float exF0 = (vf - sf) + sWfOff[wid];
  const float y0f  = sY0f;
  const float TrF  = sTotF - 0.5f * (sY0f + sYlf);
  const float invTF = 1.0f / TrF;

  // ---- obs CDF as a register chain (overwrites yo[]); publish last ----
  {
    const float invT = 1.0f / (sTotO - 0.5f * (sY0o + sYlo));
    const float hInv = 0.5f * invT;
    const float c0   = sY0o * hInv;
    float ex = exO0;
#pragma unroll
    for (int j = 0; j < EPT; ++j) {
      float yv = yo[j];
      yo[j] = fmaf(ex, invT, fmaf(yv, hInv, -c0));  // F[tid*16+j]
      ex += yv;
    }
    sFlast[tid] = yo[EPT - 1];
  }
  if (tid == 0) sQ[0] = 0.0f;  // p_0 = 0 = F_0 -> t_0 = 0
  __syncthreads();

  // ---- interval-ownership inverse CDF: thread owns (F[k0-1], F[k0]] ----
  // kprev chain is bitwise-consistent across threads (floor of the SAME
  // float value), so coverage of k=1..99 has no gaps and no overlaps.
  {
    float a = (tid == 0) ? 0.0f : sFlast[tid - 1];
    int kprev = (int)floorf(a * 99.0f);
    if (kprev < 0) kprev = 0;
    const int base = tid * EPT;
#pragma unroll
    for (int j = 0; j < EPT; ++j) {
      float b = yo[j];
      int k0 = base + j;
      int kb = (int)floorf(b * 99.0f);
      if (kb > 99) kb = 99;
      if (k0 == NT - 1) kb = 99;  // force tail coverage (np.interp clamp)
      if (kb > kprev) {
        float denom = b - a;
        float tPrev = (float)(k0 - 1) * DTIME;
        bool ok = denom > 0.f;
        float rd = ok ? 1.0f / denom : 0.0f;
        for (int k = kprev + 1; k <= kb; ++k) {
          float pk = (float)k * HF;
          float r = ok ? (pk - a) * rd : 1.0f;
          r = fminf(r, 1.0f);  // np.interp clamps beyond xp[-1]
          sQ[k] = fmaf(r, DTIME, tPrev);
        }
        kprev = kb;
      }
      a = b;
    }
  }
  __syncthreads();

  // ---- rhs of tridiag system ----
  if (tid < NM) {
    sRhs[tid] = (6.0f * 99.0f * 99.0f) *
                (sQ[tid + 2] - 2.0f * sQ[tid + 1] + sQ[tid]);
  }
  __syncthreads();

  // ---- tridiag(1,4,1) solve = 25-tap constant convolution + odd images ----
  if (tid < NM) {
    float m = 0.f;
#pragma unroll
    for (int d = -12; d <= 12; ++d) {
      int j = tid + d;
      bool neg = (j < 0), pos = (j > NM - 1);
      int jr = neg ? (-2 - j) : (pos ? (2 * NM - j) : j);
      jr = jr < 0 ? 0 : (jr > NM - 1 ? NM - 1 : jr);
      bool z = (j == -1) || (j == NM);
      float v = sRhs[jr];
      v = (neg || pos) ? -v : v;
      v = z ? 0.f : v;
      m = fmaf(GW[d < 0 ? -d : d], v, m);
    }
    sM[tid + 1] = m;
  }
  if (tid == NM) { sM[0] = 0.f; sM[NPP - 1] = 0.f; }
  __syncthreads();

  // ---- spline coefficients (float4-packed) ----
  if (tid < NPP - 1) {
    float yi = sQ[tid], yi1 = sQ[tid + 1];
    float Mi = sM[tid], Mi1 = sM[tid + 1];
    float4 co;
    co.x = yi;
    co.y = (yi1 - yi) * 99.0f - HF * (2.0f * Mi + Mi1) * (1.0f / 6.0f);
    co.z = 0.5f * Mi;
    co.w = (Mi1 - Mi) * (99.0f / 6.0f);
    sCo[tid] = co;
  }
  __syncthreads();

  // ---- Phase B: f CDF -> spline eval -> accumulation ----
  // Trapezoid boundary weights dropped: k=0 term is identically 0 and
  // k=NT-1 term is O(eps^2).
  float acc = 0.f;
  {
    const float hInv = 0.5f * invTF;
    const float c0   = y0f * hInv;
    float ex = exF0;
    const float tBase = (float)(tid * EPT) * DTIME;
#pragma unroll
    for (int j = 0; j < EPT; ++j) {
      float yv = yf[j];
      float Fk = fmaf(ex, invTF, fmaf(yv, hInv, -c0));
      ex += yv;
      float xi = fminf(fmaxf(Fk, 0.f), 1.f);
      int idx = (int)(xi * 99.0f);
      if (idx > NPP - 2) idx = NPP - 2;
      float dxv = fmaf(-(float)idx, HF, xi);
      float4 co = sCo[idx];
      float val = fmaf(dxv, fmaf(dxv, fmaf(dxv, co.w, co.z), co.y), co.x);
      float diff = fmaf((float)j, DTIME, tBase) - val;
      acc = fmaf(diff * diff, yv, acc);
    }
  }

  // ---- block reduce -> plain per-row store ----
#pragma unroll
  for (int off = 32; off > 0; off >>= 1) acc += __shfl_down(acc, off, 64);
  if (lane == 0) sWo[wid] = acc;
  __syncthreads();
  if (tid == 0) {
    rowOut[row] = (sWo[0] + sWo[1] + sWo[2] + sWo[3]) * invTF;
  }
}

// Deterministic final reduce: 2048 floats -> 1, float4 loads, double accum.
__global__ __launch_bounds__(256) void wass_reduce_kernel(
    const float* __restrict__ rowOut, float* __restrict__ out) {
  __shared__ double sW[4];
  int tid = threadIdx.x;
  int lane = tid & 63, wid = tid >> 6;
  const float4* r4 = (const float4*)rowOut;
  double acc = 0.0;
#pragma unroll
  for (int it = 0; it < NROWS / (256 * 4); ++it) {
    float4 v = r4[it * 256 + tid];
    acc += (double)v.x + (double)v.y + (double)v.z + (double)v.w;
  }
#pragma unroll
  for (int off = 32; off > 0; off >>= 1) acc += __shfl_down(acc, off, 64);
  if (lane == 0) sW[wid] = acc;
  __syncthreads();
  if (tid == 0) out[0] = (float)(sW[0] + sW[1] + sW[2] + sW[3]);
}

extern "C" void kernel_launch(void* const* d_in, const int* in_sizes, int n_in,
                              void* d_out, int out_size, void* d_ws, size_t ws_size,
                              hipStream_t stream) {
  (void)in_sizes; (void)n_in; (void)out_size; (void)ws_size;
  const float* f   = (const float*)d_in[0];
  const float* obs = (const float*)d_in[1];
  // d_in[2] (t) is analytic: t[k] = k * 0.001f — computed inline.
  float* rowOut = (float*)d_ws;  // NROWS floats, 16B-aligned

  wass_row_kernel<<<NROWS, BLK, 0, stream>>>(f, obs, rowOut);
  wass_reduce_kernel<<<1, 256, 0, stream>>>(rowOut, (float*)d_out);
}